// Round 1
// baseline (5247.393 us; speedup 1.0000x reference)
//
#include <hip/hip_runtime.h>
#include <hip/hip_bf16.h>
#include <math.h>

#define NODE_DIM  64
#define EDGE_DIM  32
#define NUM_GAUSS 16
#define HIDDEN    128
#define CAT_DIM   160   // 2*NODE_DIM + EDGE_DIM
#define TE        64    // edges per block in layer kernel

// ---------------- init: h = embed[atoms], agg = 0 ----------------
__global__ void k_init(const int* __restrict__ atoms, const float* __restrict__ embed_w,
                       float* __restrict__ h, float* __restrict__ agg, int n) {
  int stride = gridDim.x * blockDim.x;
  for (int i = blockIdx.x * blockDim.x + threadIdx.x; i < n; i += stride) {
    h[i]   = embed_w[atoms[i >> 6] * NODE_DIM + (i & 63)];
    agg[i] = 0.f;
  }
}

__global__ void k_zero(float* __restrict__ p, int n) {
  int i = blockIdx.x * blockDim.x + threadIdx.x;
  if (i < n) p[i] = 0.f;
}

// ---------------- edge precompute: dist, kind ----------------
__global__ void k_edge_pre(const int* __restrict__ src, const int* __restrict__ dst,
                           const float* __restrict__ coords, const int* __restrict__ isr,
                           float* __restrict__ dist, int* __restrict__ kind, int E) {
  int stride = gridDim.x * blockDim.x;
  for (int e = blockIdx.x * blockDim.x + threadIdx.x; e < E; e += stride) {
    int s = src[e], d = dst[e];
    float dx = coords[s*3+0] - coords[d*3+0];
    float dy = coords[s*3+1] - coords[d*3+1];
    float dz = coords[s*3+2] - coords[d*3+2];
    dist[e] = sqrtf(dx*dx + dy*dy + dz*dz);
    kind[e] = (isr[s] != isr[d]) ? 1 : 0;
  }
}

// ---------------- per-layer fused edge MLP + scatter ----------------
// block = 256 threads (4 waves), TE=64 edges per block.
// LDS: X tile [64][161] fp32 (stage A), reused as Y tile [64][129] (stage B).
__global__ __launch_bounds__(256, 2) void k_layer(
    const float* __restrict__ h, const int* __restrict__ src, const int* __restrict__ dst,
    const float* __restrict__ dist, const int* __restrict__ kind,
    const float* __restrict__ sub_w,
    const float* __restrict__ W1, const float* __restrict__ b1,
    const float* __restrict__ W2, const float* __restrict__ b2,
    float* __restrict__ agg, int E)
{
  __shared__ float smem[TE * (CAT_DIM + 1)];   // 64*161*4 = 41216 B
  __shared__ int   dste[TE];

  const int tid   = threadIdx.x;
  const int lane  = tid & 63;
  const int wv    = tid >> 6;
  const int ebase = blockIdx.x * TE;

  // ---- stage 1: gather X = [h[dst] | h[src] | edge_attr] into LDS ----
  for (int r = 0; r < TE / 4; ++r) {           // 16 edges per wave
    int e  = wv * (TE / 4) + r;
    int ge = ebase + e;
    float* row = &smem[e * (CAT_DIM + 1)];
    if (ge < E) {
      int s = src[ge], d = dst[ge];
      row[lane]      = h[(long)d * NODE_DIM + lane];
      row[64 + lane] = h[(long)s * NODE_DIM + lane];
      if (lane < NUM_GAUSS) {
        float off = 5.0f * (float)lane / 15.0f;
        float t   = dist[ge] - off;
        row[128 + lane] = __expf(-4.5f * t * t);
      } else if (lane < EDGE_DIM) {
        row[128 + lane] = sub_w[kind[ge] * NUM_GAUSS + (lane - NUM_GAUSS)];
      }
      if (lane == 0) dste[e] = d;
    } else {
      row[lane]      = 0.f;
      row[64 + lane] = 0.f;
      if (lane < EDGE_DIM) row[128 + lane] = 0.f;
      if (lane == 0) dste[e] = -1;
    }
  }
  __syncthreads();

  // ---- stage 2: Y = silu(X @ W1 + b1), register tile 4 edges x 8 hidden ----
  const int jg = tid & 15;   // hidden group: j0 = jg*8
  const int eg = tid >> 4;   // edge group:   e0 = eg*4
  const int j0 = jg * 8;
  const int e0 = eg * 4;

  float acc[4][8];
  #pragma unroll
  for (int i = 0; i < 4; ++i)
    #pragma unroll
    for (int j = 0; j < 8; ++j) acc[i][j] = 0.f;

  const float* x0 = &smem[(e0 + 0) * (CAT_DIM + 1)];
  const float* x1 = &smem[(e0 + 1) * (CAT_DIM + 1)];
  const float* x2 = &smem[(e0 + 2) * (CAT_DIM + 1)];
  const float* x3 = &smem[(e0 + 3) * (CAT_DIM + 1)];

  #pragma unroll 4
  for (int k = 0; k < CAT_DIM; ++k) {
    const float4 wa = *(const float4*)&W1[k * HIDDEN + j0];
    const float4 wb = *(const float4*)&W1[k * HIDDEN + j0 + 4];
    float xv0 = x0[k], xv1 = x1[k], xv2 = x2[k], xv3 = x3[k];
    acc[0][0] += xv0*wa.x; acc[0][1] += xv0*wa.y; acc[0][2] += xv0*wa.z; acc[0][3] += xv0*wa.w;
    acc[0][4] += xv0*wb.x; acc[0][5] += xv0*wb.y; acc[0][6] += xv0*wb.z; acc[0][7] += xv0*wb.w;
    acc[1][0] += xv1*wa.x; acc[1][1] += xv1*wa.y; acc[1][2] += xv1*wa.z; acc[1][3] += xv1*wa.w;
    acc[1][4] += xv1*wb.x; acc[1][5] += xv1*wb.y; acc[1][6] += xv1*wb.z; acc[1][7] += xv1*wb.w;
    acc[2][0] += xv2*wa.x; acc[2][1] += xv2*wa.y; acc[2][2] += xv2*wa.z; acc[2][3] += xv2*wa.w;
    acc[2][4] += xv2*wb.x; acc[2][5] += xv2*wb.y; acc[2][6] += xv2*wb.z; acc[2][7] += xv2*wb.w;
    acc[3][0] += xv3*wa.x; acc[3][1] += xv3*wa.y; acc[3][2] += xv3*wa.z; acc[3][3] += xv3*wa.w;
    acc[3][4] += xv3*wb.x; acc[3][5] += xv3*wb.y; acc[3][6] += xv3*wb.z; acc[3][7] += xv3*wb.w;
  }

  // bias + silu (in place)
  #pragma unroll
  for (int j = 0; j < 8; ++j) {
    float b = b1[j0 + j];
    #pragma unroll
    for (int i = 0; i < 4; ++i) {
      float y = acc[i][j] + b;
      acc[i][j] = y / (1.f + __expf(-y));
    }
  }
  __syncthreads();   // all X reads done before overwriting smem with Y

  #pragma unroll
  for (int i = 0; i < 4; ++i)
    #pragma unroll
    for (int j = 0; j < 8; ++j)
      smem[(e0 + i) * (HIDDEN + 1) + j0 + j] = acc[i][j];
  __syncthreads();

  // ---- stage 3: Z = Y @ W2 + b2, tile 4 edges x 4 outs, scatter-add ----
  const int og = tid & 15;
  const int o0 = og * 4;

  float accz[4][4];
  #pragma unroll
  for (int i = 0; i < 4; ++i)
    #pragma unroll
    for (int o = 0; o < 4; ++o) accz[i][o] = 0.f;

  const float* y0 = &smem[(e0 + 0) * (HIDDEN + 1)];
  const float* y1 = &smem[(e0 + 1) * (HIDDEN + 1)];
  const float* y2 = &smem[(e0 + 2) * (HIDDEN + 1)];
  const float* y3 = &smem[(e0 + 3) * (HIDDEN + 1)];

  #pragma unroll 4
  for (int k = 0; k < HIDDEN; ++k) {
    const float4 w = *(const float4*)&W2[k * NODE_DIM + o0];
    float yv0 = y0[k], yv1 = y1[k], yv2 = y2[k], yv3 = y3[k];
    accz[0][0] += yv0*w.x; accz[0][1] += yv0*w.y; accz[0][2] += yv0*w.z; accz[0][3] += yv0*w.w;
    accz[1][0] += yv1*w.x; accz[1][1] += yv1*w.y; accz[1][2] += yv1*w.z; accz[1][3] += yv1*w.w;
    accz[2][0] += yv2*w.x; accz[2][1] += yv2*w.y; accz[2][2] += yv2*w.z; accz[2][3] += yv2*w.w;
    accz[3][0] += yv3*w.x; accz[3][1] += yv3*w.y; accz[3][2] += yv3*w.z; accz[3][3] += yv3*w.w;
  }

  #pragma unroll
  for (int i = 0; i < 4; ++i) {
    int d = dste[e0 + i];
    if (d >= 0) {
      #pragma unroll
      for (int o = 0; o < 4; ++o)
        atomicAdd(&agg[(long)d * NODE_DIM + o0 + o], accz[i][o] + b2[o0 + o]);
    }
  }
}

// ---------------- residual relu + clear agg ----------------
__global__ void k_relu_update(float* __restrict__ h, float* __restrict__ agg, int n) {
  int stride = gridDim.x * blockDim.x;
  for (int i = blockIdx.x * blockDim.x + threadIdx.x; i < n; i += stride) {
    float v = h[i] + agg[i];
    h[i]   = v > 0.f ? v : 0.f;
    agg[i] = 0.f;
  }
}

// ---------------- mean pool (batch_ids sorted): wave per 64 nodes ----------------
__global__ void k_pool(const float* __restrict__ h, const int* __restrict__ batch_ids,
                       float* __restrict__ pooled, float* __restrict__ counts, int N) {
  int lane = threadIdx.x & 63;
  int base = blockIdx.x * 64;
  float acc = 0.f;
  int   cnt = 0;
  int  gcur = -1;
  for (int n = 0; n < 64; ++n) {
    int node = base + n;
    if (node >= N) break;
    int g = batch_ids[node];
    if (g != gcur) {
      if (gcur >= 0) {
        atomicAdd(&pooled[gcur * NODE_DIM + lane], acc);
        if (lane == 0) atomicAdd(&counts[gcur], (float)cnt);
      }
      gcur = g; acc = 0.f; cnt = 0;
    }
    acc += h[(long)node * NODE_DIM + lane];
    cnt++;
  }
  if (gcur >= 0) {
    atomicAdd(&pooled[gcur * NODE_DIM + lane], acc);
    if (lane == 0) atomicAdd(&counts[gcur], (float)cnt);
  }
}

// ---------------- final linear ----------------
__global__ void k_final(const float* __restrict__ pooled, const float* __restrict__ counts,
                        const float* __restrict__ fc_w, const float* __restrict__ fc_b,
                        float* __restrict__ out, int G) {
  int g = blockIdx.x * blockDim.x + threadIdx.x;
  if (g < G) {
    float acc = 0.f;
    for (int d = 0; d < NODE_DIM; ++d) acc += pooled[g * NODE_DIM + d] * fc_w[d];
    float c = counts[g];
    if (c < 1.f) c = 1.f;
    out[g] = acc / c + fc_b[0];
  }
}

extern "C" void kernel_launch(void* const* d_in, const int* in_sizes, int n_in,
                              void* d_out, int out_size, void* d_ws, size_t ws_size,
                              hipStream_t stream) {
  const int*   atoms   = (const int*)  d_in[0];
  const int*   eidx    = (const int*)  d_in[1];
  const float* coords  = (const float*)d_in[2];
  const int*   isr     = (const int*)  d_in[3];
  const int*   batch   = (const int*)  d_in[4];
  const float* embed_w = (const float*)d_in[5];
  const float* sub_w   = (const float*)d_in[6];
  const float* W1      = (const float*)d_in[7];
  const float* b1      = (const float*)d_in[8];
  const float* W2      = (const float*)d_in[9];
  const float* b2      = (const float*)d_in[10];
  const float* fc_w    = (const float*)d_in[11];
  const float* fc_b    = (const float*)d_in[12];
  float* out = (float*)d_out;

  const int N = in_sizes[0];
  const int E = in_sizes[1] / 2;
  const int L = in_sizes[8] / HIDDEN;   // = N_LAYERS
  const int G = out_size;

  const int* srcv = eidx;       // edge_index[0]
  const int* dstv = eidx + E;   // edge_index[1]

  // workspace layout (fp32)
  float* h      = (float*)d_ws;          // N*64
  float* agg    = h + (size_t)N * NODE_DIM;
  float* dist   = agg + (size_t)N * NODE_DIM;
  int*   kind   = (int*)(dist + E);
  float* pooled = (float*)(kind + E);    // G*64
  float* counts = pooled + (size_t)G * NODE_DIM;

  const int nh = N * NODE_DIM;
  k_init<<<1024, 256, 0, stream>>>(atoms, embed_w, h, agg, nh);
  k_edge_pre<<<1024, 256, 0, stream>>>(srcv, dstv, coords, isr, dist, kind, E);
  k_zero<<<(G * NODE_DIM + G + 255) / 256, 256, 0, stream>>>(pooled, G * NODE_DIM + G);

  const int nblk = (E + TE - 1) / TE;
  for (int l = 0; l < L; ++l) {
    k_layer<<<nblk, 256, 0, stream>>>(h, srcv, dstv, dist, kind, sub_w,
                                      W1 + (size_t)l * CAT_DIM * HIDDEN,
                                      b1 + (size_t)l * HIDDEN,
                                      W2 + (size_t)l * HIDDEN * NODE_DIM,
                                      b2 + (size_t)l * NODE_DIM,
                                      agg, E);
    k_relu_update<<<1024, 256, 0, stream>>>(h, agg, nh);
  }

  k_pool<<<(N + 63) / 64, 64, 0, stream>>>(h, batch, pooled, counts, N);
  k_final<<<1, 64, 0, stream>>>(pooled, counts, fc_w, fc_b, out, G);
}

// Round 2
// 2039.998 us; speedup vs baseline: 2.5723x; 2.5723x over previous
//
#include <hip/hip_runtime.h>
#include <hip/hip_bf16.h>
#include <math.h>

#define NODE_DIM  64
#define EDGE_DIM  32
#define NUM_GAUSS 16
#define HIDDEN    128
#define CAT_DIM   160
#define TE        128          // edges per block in edge-MLP kernel
#define XS        168          // X tile LDS row stride (shorts): 160 + 8 pad
#define YS        152          // Y tile LDS row stride (shorts): 128 + 24 pad
#define L1SZ      (CAT_DIM * HIDDEN)   // 20480
#define L2SZ      (HIDDEN * NODE_DIM)  // 8192

typedef __attribute__((ext_vector_type(8))) short short8;
typedef __attribute__((ext_vector_type(4))) float float4v;

static __device__ __forceinline__ short f2bf(float x) {
  __hip_bfloat16 h = __float2bfloat16(x);
  return *reinterpret_cast<short*>(&h);
}

// ---------------- init: h_f32 = embed[atoms], h_bf16 mirror ----------------
__global__ void k_init(const int* __restrict__ atoms, const float* __restrict__ embed_w,
                       float* __restrict__ hf, short* __restrict__ hb, int n) {
  int stride = gridDim.x * blockDim.x;
  for (int i = blockIdx.x * blockDim.x + threadIdx.x; i < n; i += stride) {
    float f = embed_w[atoms[i >> 6] * NODE_DIM + (i & 63)];
    hf[i] = f;
    hb[i] = f2bf(f);
  }
}

__global__ void k_zero_f(float* __restrict__ p, int n) {
  int i = blockIdx.x * blockDim.x + threadIdx.x;
  if (i < n) p[i] = 0.f;
}
__global__ void k_zero_i(int* __restrict__ p, int n) {
  int i = blockIdx.x * blockDim.x + threadIdx.x;
  if (i < n) p[i] = 0;
}

// ---------------- edge precompute: distk = (+/-)dist, sign = kind ----------------
__global__ void k_edge_pre(const int* __restrict__ src, const int* __restrict__ dst,
                           const float* __restrict__ coords, const int* __restrict__ isr,
                           float* __restrict__ distk, int E) {
  int stride = gridDim.x * blockDim.x;
  for (int e = blockIdx.x * blockDim.x + threadIdx.x; e < E; e += stride) {
    int s = src[e], d = dst[e];
    float dx = coords[s*3+0] - coords[d*3+0];
    float dy = coords[s*3+1] - coords[d*3+1];
    float dz = coords[s*3+2] - coords[d*3+2];
    float dist = sqrtf(dx*dx + dy*dy + dz*dz);
    distk[e] = (isr[s] != isr[d]) ? -dist : dist;
  }
}

// ---------------- CSR build: hist, scan, scatter-perm ----------------
__global__ void k_hist(const int* __restrict__ dst, int* __restrict__ counts, int E) {
  int stride = gridDim.x * blockDim.x;
  for (int e = blockIdx.x * blockDim.x + threadIdx.x; e < E; e += stride)
    atomicAdd(&counts[dst[e]], 1);
}

__global__ void k_scan(const int* __restrict__ counts, int* __restrict__ colptr,
                       int* __restrict__ cursor, int N, int E) {
  __shared__ int part[1024];
  int t = threadIdx.x;
  int chunk = (N + 1023) / 1024;
  int b = t * chunk, e = min(b + chunk, N);
  int s = 0;
  for (int i = b; i < e; ++i) s += counts[i];
  part[t] = s;
  __syncthreads();
  for (int o = 1; o < 1024; o <<= 1) {
    int v = (t >= o) ? part[t - o] : 0;
    __syncthreads();
    part[t] += v;
    __syncthreads();
  }
  int run = part[t] - s;   // exclusive prefix
  for (int i = b; i < e; ++i) {
    colptr[i] = run; cursor[i] = run;
    run += counts[i];
  }
  if (t == 0) colptr[N] = E;
}

__global__ void k_scatter_perm(const int* __restrict__ dst, int* __restrict__ cursor,
                               int* __restrict__ perm, int E) {
  int stride = gridDim.x * blockDim.x;
  for (int e = blockIdx.x * blockDim.x + threadIdx.x; e < E; e += stride) {
    int p = atomicAdd(&cursor[dst[e]], 1);
    perm[p] = e;
  }
}

// ---------------- weight pack to bf16 B-fragment layout ----------------
// B-frag for mfma_f32_16x16x32_bf16: lane holds k = quad*8+j (j contiguous), n = lane&15.
// packed idx = ((kt*4+quad)*NCOLS + n)*8 + j, k = kt*32+quad*8+j.
__global__ void k_pack_w1(const float* __restrict__ W, short* __restrict__ Wp, int total) {
  int i = blockIdx.x * blockDim.x + threadIdx.x;
  if (i >= total) return;
  int l = i / L1SZ, r = i % L1SZ;
  int k = r / HIDDEN, n = r % HIDDEN;
  int kt = k >> 5, quad = (k >> 3) & 3, j = k & 7;
  Wp[l * L1SZ + (((kt*4 + quad) * HIDDEN) + n) * 8 + j] = f2bf(W[i]);
}
__global__ void k_pack_w2(const float* __restrict__ W, short* __restrict__ Wp, int total) {
  int i = blockIdx.x * blockDim.x + threadIdx.x;
  if (i >= total) return;
  int l = i / L2SZ, r = i % L2SZ;
  int k = r / NODE_DIM, n = r % NODE_DIM;
  int kt = k >> 5, quad = (k >> 3) & 3, j = k & 7;
  Wp[l * L2SZ + (((kt*4 + quad) * NODE_DIM) + n) * 8 + j] = f2bf(W[i]);
}

// ---------------- edge MLP: MFMA GEMMs, dst-sorted edge order, msg out ----------------
__global__ __launch_bounds__(256, 2) void k_edge_mlp(
    const short* __restrict__ hb, const int* __restrict__ src, const int* __restrict__ dst,
    const float* __restrict__ distk, const float* __restrict__ sub_w,
    const int* __restrict__ perm,
    const short* __restrict__ W1p, const float* __restrict__ b1,
    const short* __restrict__ W2p, const float* __restrict__ b2,
    short* __restrict__ msg, int E)
{
  __shared__ short Xs[TE * XS];            // 43008 B; Y tile aliases (128*152 shorts)
  __shared__ int   se[TE], de[TE];
  __shared__ float dks[TE];

  short* Ys = Xs;

  const int tid  = threadIdx.x;
  const int lane = tid & 63;
  const int w    = tid >> 6;
  const int quad = lane >> 4;
  const int l16  = lane & 15;
  const int ebase = blockIdx.x * TE;

  // ---- stage 0: per-edge metadata via perm ----
  if (tid < TE) {
    int ge = ebase + tid;
    if (ge < E) {
      int p = perm[ge];
      se[tid] = src[p];
      de[tid] = dst[p];
      dks[tid] = distk[p];
    } else {
      se[tid] = 0; de[tid] = 0; dks[tid] = 0.f;
    }
  }
  __syncthreads();

  // ---- stage 1: gather X = [h[dst] | h[src] | edge_attr] -> LDS (bf16) ----
  // 20 chunks of 16B per edge row; 2560 chunks / 256 threads = 10 each.
  #pragma unroll
  for (int r = 0; r < (TE * 20) / 256; ++r) {
    int c = r * 256 + tid;
    int i = c / 20;
    int part = c - i * 20;
    int ge = ebase + i;
    short8 v;
    if (ge < E) {
      if (part < 16) {
        const short* p = (part < 8)
          ? hb + (size_t)de[i] * NODE_DIM + part * 8
          : hb + (size_t)se[i] * NODE_DIM + (part - 8) * 8;
        v = *reinterpret_cast<const short8*>(p);
      } else {
        float dk = dks[i];
        float dist = fabsf(dk);
        int kind = (int)(__float_as_uint(dk) >> 31);
        int c0 = (part - 16) * 8;
        #pragma unroll
        for (int jj = 0; jj < 8; ++jj) {
          int col = c0 + jj;
          float val;
          if (col < NUM_GAUSS) {
            float t = dist - (float)col * (1.0f / 3.0f);
            val = __expf(-4.5f * t * t);
          } else {
            val = sub_w[kind * NUM_GAUSS + (col - NUM_GAUSS)];
          }
          v[jj] = f2bf(val);
        }
      }
    } else {
      v = (short8)0;
    }
    *reinterpret_cast<short8*>(&Xs[i * XS + part * 8]) = v;
  }
  __syncthreads();

  // ---- stage 2: GEMM1  Y[128x128] = silu(X[128x160] @ W1 + b1) ----
  // wave w owns edge strip [w*32, w*32+32) = 2 M-tiles of 16.
  float4v acc1[2][8];
  #pragma unroll
  for (int mt = 0; mt < 2; ++mt)
    #pragma unroll
    for (int nt = 0; nt < 8; ++nt) acc1[mt][nt] = (float4v)0.f;

  #pragma unroll
  for (int kt = 0; kt < 5; ++kt) {
    short8 a0 = *reinterpret_cast<const short8*>(&Xs[(w*32 +      l16) * XS + kt*32 + quad*8]);
    short8 a1 = *reinterpret_cast<const short8*>(&Xs[(w*32 + 16 + l16) * XS + kt*32 + quad*8]);
    #pragma unroll
    for (int nt = 0; nt < 8; ++nt) {
      short8 b = *reinterpret_cast<const short8*>(&W1p[(((kt*4 + quad) * HIDDEN) + nt*16 + l16) * 8]);
      acc1[0][nt] = __builtin_amdgcn_mfma_f32_16x16x32_bf16(a0, b, acc1[0][nt], 0, 0, 0);
      acc1[1][nt] = __builtin_amdgcn_mfma_f32_16x16x32_bf16(a1, b, acc1[1][nt], 0, 0, 0);
    }
  }

  // bias + silu in place
  #pragma unroll
  for (int nt = 0; nt < 8; ++nt) {
    float bb = b1[nt*16 + l16];
    #pragma unroll
    for (int mt = 0; mt < 2; ++mt)
      #pragma unroll
      for (int r = 0; r < 4; ++r) {
        float y = acc1[mt][nt][r] + bb;
        acc1[mt][nt][r] = y * __builtin_amdgcn_rcpf(1.f + __expf(-y));
      }
  }
  __syncthreads();   // everyone done reading X before Y overwrites it

  // C-layout: row = strip + mt*16 + quad*4 + r, col = nt*16 + l16
  #pragma unroll
  for (int mt = 0; mt < 2; ++mt)
    #pragma unroll
    for (int nt = 0; nt < 8; ++nt)
      #pragma unroll
      for (int r = 0; r < 4; ++r)
        Ys[(w*32 + mt*16 + quad*4 + r) * YS + nt*16 + l16] = f2bf(acc1[mt][nt][r]);
  __syncthreads();

  // ---- stage 3: GEMM2  Z[128x64] = Y[128x128] @ W2 + b2 ----
  float4v acc2[2][4];
  #pragma unroll
  for (int mt = 0; mt < 2; ++mt)
    #pragma unroll
    for (int nt = 0; nt < 4; ++nt) acc2[mt][nt] = (float4v)0.f;

  #pragma unroll
  for (int kt = 0; kt < 4; ++kt) {
    short8 a0 = *reinterpret_cast<const short8*>(&Ys[(w*32 +      l16) * YS + kt*32 + quad*8]);
    short8 a1 = *reinterpret_cast<const short8*>(&Ys[(w*32 + 16 + l16) * YS + kt*32 + quad*8]);
    #pragma unroll
    for (int nt = 0; nt < 4; ++nt) {
      short8 b = *reinterpret_cast<const short8*>(&W2p[(((kt*4 + quad) * NODE_DIM) + nt*16 + l16) * 8]);
      acc2[0][nt] = __builtin_amdgcn_mfma_f32_16x16x32_bf16(a0, b, acc2[0][nt], 0, 0, 0);
      acc2[1][nt] = __builtin_amdgcn_mfma_f32_16x16x32_bf16(a1, b, acc2[1][nt], 0, 0, 0);
    }
  }

  // ---- epilogue: msg[ge][col] = Z + b2 (bf16, dst-sorted row order) ----
  #pragma unroll
  for (int nt = 0; nt < 4; ++nt) {
    float bb = b2[nt*16 + l16];
    #pragma unroll
    for (int mt = 0; mt < 2; ++mt)
      #pragma unroll
      for (int r = 0; r < 4; ++r) {
        int row = w*32 + mt*16 + quad*4 + r;
        int ge = ebase + row;
        if (ge < E)
          msg[(size_t)ge * NODE_DIM + nt*16 + l16] = f2bf(acc2[mt][nt][r] + bb);
      }
  }
}

// ---------------- aggregate: wave per node, contiguous msg rows, fused relu ----------------
__global__ void k_aggregate(const short* __restrict__ msg, const int* __restrict__ colptr,
                            float* __restrict__ hf, short* __restrict__ hb, int N) {
  int tid  = threadIdx.x;
  int lane = tid & 63;
  int n = blockIdx.x * 4 + (tid >> 6);
  if (n >= N) return;
  int half = lane >> 5;
  int l32  = lane & 31;

  int s = colptr[n], e = colptr[n + 1];
  float a0 = 0.f, a1 = 0.f;
  for (int j = s; j < e; j += 2) {
    int r = j + half;
    if (r < e) {
      unsigned int u = *reinterpret_cast<const unsigned int*>(&msg[(size_t)r * NODE_DIM + l32 * 2]);
      a0 += __uint_as_float(u << 16);
      a1 += __uint_as_float(u & 0xffff0000u);
    }
  }
  a0 += __shfl_xor(a0, 32);
  a1 += __shfl_xor(a1, 32);

  if (half == 0) {
    size_t idx = (size_t)n * NODE_DIM + l32 * 2;
    float2 hv = *reinterpret_cast<float2*>(&hf[idx]);
    float v0 = hv.x + a0, v1 = hv.y + a1;
    v0 = v0 > 0.f ? v0 : 0.f;
    v1 = v1 > 0.f ? v1 : 0.f;
    *reinterpret_cast<float2*>(&hf[idx]) = make_float2(v0, v1);
    unsigned int pk = ((unsigned int)(unsigned short)f2bf(v1) << 16) | (unsigned short)f2bf(v0);
    *reinterpret_cast<unsigned int*>(&hb[idx]) = pk;
  }
}

// ---------------- mean pool (batch_ids sorted): wave per 64 nodes ----------------
__global__ void k_pool(const float* __restrict__ h, const int* __restrict__ batch_ids,
                       float* __restrict__ pooled, float* __restrict__ counts, int N) {
  int lane = threadIdx.x & 63;
  int base = blockIdx.x * 64;
  float acc = 0.f;
  int   cnt = 0;
  int  gcur = -1;
  for (int n = 0; n < 64; ++n) {
    int node = base + n;
    if (node >= N) break;
    int g = batch_ids[node];
    if (g != gcur) {
      if (gcur >= 0) {
        atomicAdd(&pooled[gcur * NODE_DIM + lane], acc);
        if (lane == 0) atomicAdd(&counts[gcur], (float)cnt);
      }
      gcur = g; acc = 0.f; cnt = 0;
    }
    acc += h[(size_t)node * NODE_DIM + lane];
    cnt++;
  }
  if (gcur >= 0) {
    atomicAdd(&pooled[gcur * NODE_DIM + lane], acc);
    if (lane == 0) atomicAdd(&counts[gcur], (float)cnt);
  }
}

__global__ void k_final(const float* __restrict__ pooled, const float* __restrict__ counts,
                        const float* __restrict__ fc_w, const float* __restrict__ fc_b,
                        float* __restrict__ out, int G) {
  int g = blockIdx.x * blockDim.x + threadIdx.x;
  if (g < G) {
    float acc = 0.f;
    for (int d = 0; d < NODE_DIM; ++d) acc += pooled[g * NODE_DIM + d] * fc_w[d];
    float c = counts[g];
    if (c < 1.f) c = 1.f;
    out[g] = acc / c + fc_b[0];
  }
}

extern "C" void kernel_launch(void* const* d_in, const int* in_sizes, int n_in,
                              void* d_out, int out_size, void* d_ws, size_t ws_size,
                              hipStream_t stream) {
  const int*   atoms   = (const int*)  d_in[0];
  const int*   eidx    = (const int*)  d_in[1];
  const float* coords  = (const float*)d_in[2];
  const int*   isr     = (const int*)  d_in[3];
  const int*   batch   = (const int*)  d_in[4];
  const float* embed_w = (const float*)d_in[5];
  const float* sub_w   = (const float*)d_in[6];
  const float* W1      = (const float*)d_in[7];
  const float* b1      = (const float*)d_in[8];
  const float* W2      = (const float*)d_in[9];
  const float* b2      = (const float*)d_in[10];
  const float* fc_w    = (const float*)d_in[11];
  const float* fc_b    = (const float*)d_in[12];
  float* out = (float*)d_out;

  const int N = in_sizes[0];
  const int E = in_sizes[1] / 2;
  const int L = in_sizes[8] / HIDDEN;
  const int G = out_size;

  const int* srcv = eidx;
  const int* dstv = eidx + E;

  // workspace carve, 256B-aligned
  size_t off = 0;
  auto carve = [&](size_t bytes) -> char* {
    char* p = (char*)d_ws + off;
    off += (bytes + 255) & ~(size_t)255;
    return p;
  };
  float* hf      = (float*)carve((size_t)N * NODE_DIM * 4);
  short* hb      = (short*)carve((size_t)N * NODE_DIM * 2);
  float* distk   = (float*)carve((size_t)E * 4);
  int*   cnts    = (int*)  carve((size_t)N * 4);
  int*   colptr  = (int*)  carve((size_t)(N + 1) * 4);
  int*   cursor  = (int*)  carve((size_t)N * 4);
  int*   perm    = (int*)  carve((size_t)E * 4);
  short* W1p     = (short*)carve((size_t)L * L1SZ * 2);
  short* W2p     = (short*)carve((size_t)L * L2SZ * 2);
  short* msg     = (short*)carve((size_t)E * NODE_DIM * 2);
  float* pooled  = (float*)carve((size_t)G * NODE_DIM * 4);
  float* cntg    = (float*)carve((size_t)G * 4);

  const int nh = N * NODE_DIM;
  k_init<<<1024, 256, 0, stream>>>(atoms, embed_w, hf, hb, nh);
  k_edge_pre<<<1024, 256, 0, stream>>>(srcv, dstv, coords, isr, distk, E);
  k_zero_i<<<(N + 255) / 256, 256, 0, stream>>>(cnts, N);
  k_zero_f<<<(G * NODE_DIM + G + 255) / 256, 256, 0, stream>>>(pooled, G * NODE_DIM + G);
  k_hist<<<1024, 256, 0, stream>>>(dstv, cnts, E);
  k_scan<<<1, 1024, 0, stream>>>(cnts, colptr, cursor, N, E);
  k_scatter_perm<<<1024, 256, 0, stream>>>(dstv, cursor, perm, E);
  k_pack_w1<<<(L * L1SZ + 255) / 256, 256, 0, stream>>>(W1, W1p, L * L1SZ);
  k_pack_w2<<<(L * L2SZ + 255) / 256, 256, 0, stream>>>(W2, W2p, L * L2SZ);

  const int nblk = (E + TE - 1) / TE;
  const int ablk = (N + 3) / 4;
  for (int l = 0; l < L; ++l) {
    k_edge_mlp<<<nblk, 256, 0, stream>>>(hb, srcv, dstv, distk, sub_w, perm,
                                         W1p + (size_t)l * L1SZ, b1 + (size_t)l * HIDDEN,
                                         W2p + (size_t)l * L2SZ, b2 + (size_t)l * NODE_DIM,
                                         msg, E);
    k_aggregate<<<ablk, 256, 0, stream>>>(msg, colptr, hf, hb, N);
  }

  k_pool<<<(N + 63) / 64, 64, 0, stream>>>(hf, batch, pooled, cntg, N);
  k_final<<<1, 64, 0, stream>>>(pooled, cntg, fc_w, fc_b, out, G);
}

// Round 3
// 1282.004 us; speedup vs baseline: 4.0931x; 1.5913x over previous
//
#include <hip/hip_runtime.h>
#include <hip/hip_bf16.h>
#include <math.h>

#define NODE_DIM  64
#define EDGE_DIM  32
#define NUM_GAUSS 16
#define HIDDEN    128
#define CAT_DIM   160
#define TE        128          // edges per block in edge-MLP kernel
#define YS        136          // Y tile LDS row stride (shorts): 128 + 8 pad
#define L1SZ      (CAT_DIM * HIDDEN)   // 20480
#define L2SZ      (HIDDEN * NODE_DIM)  // 8192

typedef __attribute__((ext_vector_type(8))) short short8;
typedef __attribute__((ext_vector_type(4))) float float4v;

static __device__ __forceinline__ short f2bf(float x) {
  __hip_bfloat16 h = __float2bfloat16(x);
  return *reinterpret_cast<short*>(&h);
}

// ---------------- init: h_f32 = embed[atoms], h_bf16 mirror, agg = 0 ----------------
__global__ void k_init(const int* __restrict__ atoms, const float* __restrict__ embed_w,
                       float* __restrict__ hf, short* __restrict__ hb,
                       float* __restrict__ agg, int n) {
  int stride = gridDim.x * blockDim.x;
  for (int i = blockIdx.x * blockDim.x + threadIdx.x; i < n; i += stride) {
    float f = embed_w[atoms[i >> 6] * NODE_DIM + (i & 63)];
    hf[i]  = f;
    hb[i]  = f2bf(f);
    agg[i] = 0.f;
  }
}

__global__ void k_zero_f(float* __restrict__ p, int n) {
  int i = blockIdx.x * blockDim.x + threadIdx.x;
  if (i < n) p[i] = 0.f;
}
__global__ void k_zero_i(int* __restrict__ p, int n) {
  int i = blockIdx.x * blockDim.x + threadIdx.x;
  if (i < n) p[i] = 0;
}

// ---------------- edge precompute: distk = (+/-)dist, sign encodes kind ----------------
__global__ void k_edge_pre(const int* __restrict__ src, const int* __restrict__ dst,
                           const float* __restrict__ coords, const int* __restrict__ isr,
                           float* __restrict__ distk, int E) {
  int stride = gridDim.x * blockDim.x;
  for (int e = blockIdx.x * blockDim.x + threadIdx.x; e < E; e += stride) {
    int s = src[e], d = dst[e];
    float dx = coords[s*3+0] - coords[d*3+0];
    float dy = coords[s*3+1] - coords[d*3+1];
    float dz = coords[s*3+2] - coords[d*3+2];
    float dist = sqrtf(dx*dx + dy*dy + dz*dz);
    distk[e] = (isr[s] != isr[d]) ? -dist : dist;
  }
}

// ---------------- CSR-order build: hist, scan, scatter permuted edge arrays ----------------
__global__ void k_hist(const int* __restrict__ dst, int* __restrict__ counts, int E) {
  int stride = gridDim.x * blockDim.x;
  for (int e = blockIdx.x * blockDim.x + threadIdx.x; e < E; e += stride)
    atomicAdd(&counts[dst[e]], 1);
}

__global__ void k_scan(const int* __restrict__ counts, int* __restrict__ cursor, int N) {
  __shared__ int part[1024];
  int t = threadIdx.x;
  int chunk = (N + 1023) / 1024;
  int b = t * chunk, e = min(b + chunk, N);
  int s = 0;
  for (int i = b; i < e; ++i) s += counts[i];
  part[t] = s;
  __syncthreads();
  for (int o = 1; o < 1024; o <<= 1) {
    int v = (t >= o) ? part[t - o] : 0;
    __syncthreads();
    part[t] += v;
    __syncthreads();
  }
  int run = part[t] - s;   // exclusive prefix
  for (int i = b; i < e; ++i) {
    cursor[i] = run;
    run += counts[i];
  }
}

// scatter edges into dst-sorted order, materializing permuted arrays
__global__ void k_build(const int* __restrict__ src, const int* __restrict__ dst,
                        const float* __restrict__ distk, int* __restrict__ cursor,
                        int* __restrict__ se_p, int* __restrict__ de_p,
                        float* __restrict__ dk_p, int E) {
  int stride = gridDim.x * blockDim.x;
  for (int e = blockIdx.x * blockDim.x + threadIdx.x; e < E; e += stride) {
    int d = dst[e];
    int p = atomicAdd(&cursor[d], 1);
    se_p[p] = src[e];
    de_p[p] = d;
    dk_p[p] = distk[e];
  }
}

// ---------------- weight pack to bf16 B-fragment layout ----------------
// B-frag for mfma_f32_16x16x32_bf16: lane holds k = quad*8+j (j contiguous), n = lane&15.
// packed idx = ((kt*4+quad)*NCOLS + n)*8 + j, k = kt*32+quad*8+j.
__global__ void k_pack_w1(const float* __restrict__ W, short* __restrict__ Wp, int total) {
  int i = blockIdx.x * blockDim.x + threadIdx.x;
  if (i >= total) return;
  int l = i / L1SZ, r = i % L1SZ;
  int k = r / HIDDEN, n = r % HIDDEN;
  int kt = k >> 5, quad = (k >> 3) & 3, j = k & 7;
  Wp[l * L1SZ + (((kt*4 + quad) * HIDDEN) + n) * 8 + j] = f2bf(W[i]);
}
__global__ void k_pack_w2(const float* __restrict__ W, short* __restrict__ Wp, int total) {
  int i = blockIdx.x * blockDim.x + threadIdx.x;
  if (i >= total) return;
  int l = i / L2SZ, r = i % L2SZ;
  int k = r / NODE_DIM, n = r % NODE_DIM;
  int kt = k >> 5, quad = (k >> 3) & 3, j = k & 7;
  Wp[l * L2SZ + (((kt*4 + quad) * NODE_DIM) + n) * 8 + j] = f2bf(W[i]);
}

// ---------------- edge MLP: barrier-free MFMA, direct-global A, fused scatter ----------------
__global__ __launch_bounds__(256, 4) void k_edge_mlp(
    const short* __restrict__ hb,
    const int* __restrict__ se_p, const int* __restrict__ de_p,
    const float* __restrict__ dk_p, const float* __restrict__ sub_w,
    const short* __restrict__ W1p, const float* __restrict__ b1,
    const short* __restrict__ W2p, const float* __restrict__ b2,
    float* __restrict__ agg, int E)
{
  __shared__ short Ys[TE * YS];   // 34816 B, wave-private 32-row strips

  const int tid  = threadIdx.x;
  const int lane = tid & 63;
  const int w    = tid >> 6;
  const int quad = lane >> 4;
  const int l16  = lane & 15;
  const int ebase = blockIdx.x * TE;

  // ---- per-lane A-row metadata (rows w*32+l16 and +16), sequential global reads ----
  const int r0 = ebase + w*32 + l16;
  const int r1 = r0 + 16;
  const bool v0 = r0 < E, v1 = r1 < E;
  const int se0 = v0 ? se_p[r0] : 0;
  const int se1 = v1 ? se_p[r1] : 0;
  const int de0 = v0 ? de_p[r0] : 0;
  const int de1 = v1 ? de_p[r1] : 0;
  const float dk0 = v0 ? dk_p[r0] : 0.f;
  const float dk1 = v1 ? dk_p[r1] : 0.f;

  // ---- edge-attr A fragment (k = 128 + quad*8 + j) ----
  const int c0 = quad * 8;
  short8 ea0, ea1;
  if (quad < 2) {
    #pragma unroll
    for (int j = 0; j < 8; ++j) {
      float t0 = fabsf(dk0) - (float)(c0 + j) * (1.0f / 3.0f);
      float t1 = fabsf(dk1) - (float)(c0 + j) * (1.0f / 3.0f);
      ea0[j] = f2bf(__expf(-4.5f * t0 * t0));
      ea1[j] = f2bf(__expf(-4.5f * t1 * t1));
    }
  } else {
    int k0 = (int)(__float_as_uint(dk0) >> 31);
    int k1 = (int)(__float_as_uint(dk1) >> 31);
    const float* s0 = &sub_w[k0 * NUM_GAUSS + (c0 - 16)];
    const float* s1 = &sub_w[k1 * NUM_GAUSS + (c0 - 16)];
    #pragma unroll
    for (int j = 0; j < 8; ++j) { ea0[j] = f2bf(s0[j]); ea1[j] = f2bf(s1[j]); }
  }

  const short* pd0 = hb + (size_t)de0 * NODE_DIM;
  const short* pd1 = hb + (size_t)de1 * NODE_DIM;
  const short* ps0 = hb + (size_t)se0 * NODE_DIM;
  const short* ps1 = hb + (size_t)se1 * NODE_DIM;
  const int koff = quad * 8;

  // ---- GEMM1: Y[128x128] = silu(X @ W1 + b1), A direct from global ----
  float4v acc1[2][8];
  #pragma unroll
  for (int mt = 0; mt < 2; ++mt)
    #pragma unroll
    for (int nt = 0; nt < 8; ++nt) acc1[mt][nt] = (float4v)0.f;

  #pragma unroll
  for (int kt = 0; kt < 5; ++kt) {
    short8 a0, a1;
    if (kt == 0)      { a0 = *(const short8*)(pd0 + koff);      a1 = *(const short8*)(pd1 + koff); }
    else if (kt == 1) { a0 = *(const short8*)(pd0 + 32 + koff); a1 = *(const short8*)(pd1 + 32 + koff); }
    else if (kt == 2) { a0 = *(const short8*)(ps0 + koff);      a1 = *(const short8*)(ps1 + koff); }
    else if (kt == 3) { a0 = *(const short8*)(ps0 + 32 + koff); a1 = *(const short8*)(ps1 + 32 + koff); }
    else              { a0 = ea0;                               a1 = ea1; }
    #pragma unroll
    for (int nt = 0; nt < 8; ++nt) {
      short8 b = *(const short8*)&W1p[(((kt*4 + quad) * HIDDEN) + nt*16 + l16) * 8];
      acc1[0][nt] = __builtin_amdgcn_mfma_f32_16x16x32_bf16(a0, b, acc1[0][nt], 0, 0, 0);
      acc1[1][nt] = __builtin_amdgcn_mfma_f32_16x16x32_bf16(a1, b, acc1[1][nt], 0, 0, 0);
    }
  }

  // bias + silu, write Y to wave-private LDS strip (C-layout -> A-layout transform)
  #pragma unroll
  for (int nt = 0; nt < 8; ++nt) {
    float bb = b1[nt*16 + l16];
    #pragma unroll
    for (int mt = 0; mt < 2; ++mt)
      #pragma unroll
      for (int r = 0; r < 4; ++r) {
        float y = acc1[mt][nt][r] + bb;
        y = y * __builtin_amdgcn_rcpf(1.f + __expf(-y));
        Ys[(w*32 + mt*16 + quad*4 + r) * YS + nt*16 + l16] = f2bf(y);
      }
  }
  // wave-private strip: within-wave lgkmcnt ordering suffices, no barrier

  // ---- GEMM2: Z[128x64] = Y @ W2 ----
  float4v acc2[2][4];
  #pragma unroll
  for (int mt = 0; mt < 2; ++mt)
    #pragma unroll
    for (int nt = 0; nt < 4; ++nt) acc2[mt][nt] = (float4v)0.f;

  #pragma unroll
  for (int kt = 0; kt < 4; ++kt) {
    short8 a0 = *(const short8*)&Ys[(w*32 +      l16) * YS + kt*32 + quad*8];
    short8 a1 = *(const short8*)&Ys[(w*32 + 16 + l16) * YS + kt*32 + quad*8];
    #pragma unroll
    for (int nt = 0; nt < 4; ++nt) {
      short8 b = *(const short8*)&W2p[(((kt*4 + quad) * NODE_DIM) + nt*16 + l16) * 8];
      acc2[0][nt] = __builtin_amdgcn_mfma_f32_16x16x32_bf16(a0, b, acc2[0][nt], 0, 0, 0);
      acc2[1][nt] = __builtin_amdgcn_mfma_f32_16x16x32_bf16(a1, b, acc2[1][nt], 0, 0, 0);
    }
  }

  // ---- fused epilogue: run-length reduce over 4 dst-sorted rows, atomicAdd fp32 ----
  #pragma unroll
  for (int mt = 0; mt < 2; ++mt) {
    const int rbase = ebase + w*32 + mt*16 + quad*4;
    int d[4];
    #pragma unroll
    for (int r = 0; r < 4; ++r) d[r] = (rbase + r < E) ? de_p[rbase + r] : -1;
    #pragma unroll
    for (int nt = 0; nt < 4; ++nt) {
      const int col = nt*16 + l16;
      const float bb = b2[col];
      float run = 0.f;
      int cur = d[0];
      #pragma unroll
      for (int r = 0; r < 4; ++r) {
        if (d[r] != cur) {
          if (cur >= 0) atomicAdd(&agg[(size_t)cur * NODE_DIM + col], run);
          run = 0.f; cur = d[r];
        }
        run += acc2[mt][nt][r] + bb;
      }
      if (cur >= 0) atomicAdd(&agg[(size_t)cur * NODE_DIM + col], run);
    }
  }
}

// ---------------- residual relu + refresh bf16 mirror + clear agg ----------------
__global__ void k_relu_update(float* __restrict__ hf, short* __restrict__ hb,
                              float* __restrict__ agg, int n4) {
  int stride = gridDim.x * blockDim.x;
  for (int i = blockIdx.x * blockDim.x + threadIdx.x; i < n4; i += stride) {
    float4 a = *reinterpret_cast<float4*>(&agg[i * 4]);
    float4 h = *reinterpret_cast<float4*>(&hf[i * 4]);
    float x0 = fmaxf(h.x + a.x, 0.f), x1 = fmaxf(h.y + a.y, 0.f);
    float x2 = fmaxf(h.z + a.z, 0.f), x3 = fmaxf(h.w + a.w, 0.f);
    *reinterpret_cast<float4*>(&hf[i * 4]) = make_float4(x0, x1, x2, x3);
    unsigned int p0 = ((unsigned int)(unsigned short)f2bf(x1) << 16) | (unsigned short)f2bf(x0);
    unsigned int p1 = ((unsigned int)(unsigned short)f2bf(x3) << 16) | (unsigned short)f2bf(x2);
    *reinterpret_cast<uint2*>(&hb[i * 4]) = make_uint2(p0, p1);
    *reinterpret_cast<float4*>(&agg[i * 4]) = make_float4(0.f, 0.f, 0.f, 0.f);
  }
}

// ---------------- mean pool (batch_ids sorted): wave per 64 nodes ----------------
__global__ void k_pool(const float* __restrict__ h, const int* __restrict__ batch_ids,
                       float* __restrict__ pooled, float* __restrict__ counts, int N) {
  int lane = threadIdx.x & 63;
  int base = blockIdx.x * 64;
  float acc = 0.f;
  int   cnt = 0;
  int  gcur = -1;
  for (int n = 0; n < 64; ++n) {
    int node = base + n;
    if (node >= N) break;
    int g = batch_ids[node];
    if (g != gcur) {
      if (gcur >= 0) {
        atomicAdd(&pooled[gcur * NODE_DIM + lane], acc);
        if (lane == 0) atomicAdd(&counts[gcur], (float)cnt);
      }
      gcur = g; acc = 0.f; cnt = 0;
    }
    acc += h[(size_t)node * NODE_DIM + lane];
    cnt++;
  }
  if (gcur >= 0) {
    atomicAdd(&pooled[gcur * NODE_DIM + lane], acc);
    if (lane == 0) atomicAdd(&counts[gcur], (float)cnt);
  }
}

__global__ void k_final(const float* __restrict__ pooled, const float* __restrict__ counts,
                        const float* __restrict__ fc_w, const float* __restrict__ fc_b,
                        float* __restrict__ out, int G) {
  int g = blockIdx.x * blockDim.x + threadIdx.x;
  if (g < G) {
    float acc = 0.f;
    for (int d = 0; d < NODE_DIM; ++d) acc += pooled[g * NODE_DIM + d] * fc_w[d];
    float c = counts[g];
    if (c < 1.f) c = 1.f;
    out[g] = acc / c + fc_b[0];
  }
}

extern "C" void kernel_launch(void* const* d_in, const int* in_sizes, int n_in,
                              void* d_out, int out_size, void* d_ws, size_t ws_size,
                              hipStream_t stream) {
  const int*   atoms   = (const int*)  d_in[0];
  const int*   eidx    = (const int*)  d_in[1];
  const float* coords  = (const float*)d_in[2];
  const int*   isr     = (const int*)  d_in[3];
  const int*   batch   = (const int*)  d_in[4];
  const float* embed_w = (const float*)d_in[5];
  const float* sub_w   = (const float*)d_in[6];
  const float* W1      = (const float*)d_in[7];
  const float* b1      = (const float*)d_in[8];
  const float* W2      = (const float*)d_in[9];
  const float* b2      = (const float*)d_in[10];
  const float* fc_w    = (const float*)d_in[11];
  const float* fc_b    = (const float*)d_in[12];
  float* out = (float*)d_out;

  const int N = in_sizes[0];
  const int E = in_sizes[1] / 2;
  const int L = in_sizes[8] / HIDDEN;
  const int G = out_size;

  const int* srcv = eidx;
  const int* dstv = eidx + E;

  size_t off = 0;
  auto carve = [&](size_t bytes) -> char* {
    char* p = (char*)d_ws + off;
    off += (bytes + 255) & ~(size_t)255;
    return p;
  };
  float* hf      = (float*)carve((size_t)N * NODE_DIM * 4);
  short* hb      = (short*)carve((size_t)N * NODE_DIM * 2);
  float* agg     = (float*)carve((size_t)N * NODE_DIM * 4);
  float* distk   = (float*)carve((size_t)E * 4);
  int*   cnts    = (int*)  carve((size_t)N * 4);
  int*   cursor  = (int*)  carve((size_t)N * 4);
  int*   se_p    = (int*)  carve((size_t)E * 4);
  int*   de_p    = (int*)  carve((size_t)E * 4);
  float* dk_p    = (float*)carve((size_t)E * 4);
  short* W1p     = (short*)carve((size_t)L * L1SZ * 2);
  short* W2p     = (short*)carve((size_t)L * L2SZ * 2);
  float* pooled  = (float*)carve((size_t)G * NODE_DIM * 4);
  float* cntg    = (float*)carve((size_t)G * 4);

  const int nh = N * NODE_DIM;
  k_init<<<1024, 256, 0, stream>>>(atoms, embed_w, hf, hb, agg, nh);
  k_edge_pre<<<1024, 256, 0, stream>>>(srcv, dstv, coords, isr, distk, E);
  k_zero_i<<<(N + 255) / 256, 256, 0, stream>>>(cnts, N);
  k_zero_f<<<(G * NODE_DIM + G + 255) / 256, 256, 0, stream>>>(pooled, G * NODE_DIM + G);
  k_hist<<<1024, 256, 0, stream>>>(dstv, cnts, E);
  k_scan<<<1, 1024, 0, stream>>>(cnts, cursor, N);
  k_build<<<1024, 256, 0, stream>>>(srcv, dstv, distk, cursor, se_p, de_p, dk_p, E);
  k_pack_w1<<<(L * L1SZ + 255) / 256, 256, 0, stream>>>(W1, W1p, L * L1SZ);
  k_pack_w2<<<(L * L2SZ + 255) / 256, 256, 0, stream>>>(W2, W2p, L * L2SZ);

  const int nblk = (E + TE - 1) / TE;
  for (int l = 0; l < L; ++l) {
    k_edge_mlp<<<nblk, 256, 0, stream>>>(hb, se_p, de_p, dk_p, sub_w,
                                         W1p + (size_t)l * L1SZ, b1 + (size_t)l * HIDDEN,
                                         W2p + (size_t)l * L2SZ, b2 + (size_t)l * NODE_DIM,
                                         agg, E);
    k_relu_update<<<1024, 256, 0, stream>>>(hf, hb, agg, nh / 4);
  }

  k_pool<<<(N + 63) / 64, 64, 0, stream>>>(hf, batch, pooled, cntg, N);
  k_final<<<1, 64, 0, stream>>>(pooled, cntg, fc_w, fc_b, out, G);
}

// Round 4
// 1215.128 us; speedup vs baseline: 4.3184x; 1.0550x over previous
//
#include <hip/hip_runtime.h>
#include <hip/hip_bf16.h>
#include <math.h>

#define NODE_DIM  64
#define EDGE_DIM  32
#define NUM_GAUSS 16
#define HIDDEN    128
#define CAT_DIM   160
#define TE        256          // edges per block
#define YS        136          // Y tile LDS row stride (shorts): 128 + 8 pad (272 B/row)
#define ZS        68           // Z tile row stride (floats): 64 + 4 pad (272 B/row, aliases Ys)
#define L1SZ      (CAT_DIM * HIDDEN)   // 20480
#define L2SZ      (HIDDEN * NODE_DIM)  // 8192

typedef __attribute__((ext_vector_type(8))) short short8;
typedef __attribute__((ext_vector_type(4))) float float4v;

static __device__ __forceinline__ short f2bf(float x) {
  __hip_bfloat16 h = __float2bfloat16(x);
  return *reinterpret_cast<short*>(&h);
}

// ---------------- init: h_f32 = embed[atoms], h_bf16 mirror, agg = 0 ----------------
__global__ void k_init(const int* __restrict__ atoms, const float* __restrict__ embed_w,
                       float* __restrict__ hf, short* __restrict__ hb,
                       float* __restrict__ agg, int n) {
  int stride = gridDim.x * blockDim.x;
  for (int i = blockIdx.x * blockDim.x + threadIdx.x; i < n; i += stride) {
    float f = embed_w[atoms[i >> 6] * NODE_DIM + (i & 63)];
    hf[i]  = f;
    hb[i]  = f2bf(f);
    agg[i] = 0.f;
  }
}

__global__ void k_zero_f(float* __restrict__ p, int n) {
  int i = blockIdx.x * blockDim.x + threadIdx.x;
  if (i < n) p[i] = 0.f;
}
__global__ void k_zero_i(int* __restrict__ p, int n) {
  int i = blockIdx.x * blockDim.x + threadIdx.x;
  if (i < n) p[i] = 0;
}

// ---------------- edge precompute: distk = (+/-)dist, sign encodes kind ----------------
__global__ void k_edge_pre(const int* __restrict__ src, const int* __restrict__ dst,
                           const float* __restrict__ coords, const int* __restrict__ isr,
                           float* __restrict__ distk, int E) {
  int stride = gridDim.x * blockDim.x;
  for (int e = blockIdx.x * blockDim.x + threadIdx.x; e < E; e += stride) {
    int s = src[e], d = dst[e];
    float dx = coords[s*3+0] - coords[d*3+0];
    float dy = coords[s*3+1] - coords[d*3+1];
    float dz = coords[s*3+2] - coords[d*3+2];
    float dist = sqrtf(dx*dx + dy*dy + dz*dz);
    distk[e] = (isr[s] != isr[d]) ? -dist : dist;
  }
}

// ---------------- CSR-order build: hist, scan, scatter permuted edge arrays ----------------
__global__ void k_hist(const int* __restrict__ dst, int* __restrict__ counts, int E) {
  int stride = gridDim.x * blockDim.x;
  for (int e = blockIdx.x * blockDim.x + threadIdx.x; e < E; e += stride)
    atomicAdd(&counts[dst[e]], 1);
}

__global__ void k_scan(const int* __restrict__ counts, int* __restrict__ cursor, int N) {
  __shared__ int part[1024];
  int t = threadIdx.x;
  int chunk = (N + 1023) / 1024;
  int b = t * chunk, e = min(b + chunk, N);
  int s = 0;
  for (int i = b; i < e; ++i) s += counts[i];
  part[t] = s;
  __syncthreads();
  for (int o = 1; o < 1024; o <<= 1) {
    int v = (t >= o) ? part[t - o] : 0;
    __syncthreads();
    part[t] += v;
    __syncthreads();
  }
  int run = part[t] - s;   // exclusive prefix
  for (int i = b; i < e; ++i) {
    cursor[i] = run;
    run += counts[i];
  }
}

// scatter edges into dst-sorted order, materializing permuted arrays
__global__ void k_build(const int* __restrict__ src, const int* __restrict__ dst,
                        const float* __restrict__ distk, int* __restrict__ cursor,
                        int* __restrict__ se_p, int* __restrict__ de_p,
                        float* __restrict__ dk_p, int E) {
  int stride = gridDim.x * blockDim.x;
  for (int e = blockIdx.x * blockDim.x + threadIdx.x; e < E; e += stride) {
    int d = dst[e];
    int p = atomicAdd(&cursor[d], 1);
    se_p[p] = src[e];
    de_p[p] = d;
    dk_p[p] = distk[e];
  }
}

// ---------------- weight pack to bf16 B-fragment layout ----------------
// B-frag for mfma_f32_16x16x32_bf16: lane holds k = quad*8+j (j contiguous), n = lane&15.
// packed idx = ((kt*4+quad)*NCOLS + n)*8 + j, k = kt*32+quad*8+j.
__global__ void k_pack_w1(const float* __restrict__ W, short* __restrict__ Wp, int total) {
  int i = blockIdx.x * blockDim.x + threadIdx.x;
  if (i >= total) return;
  int l = i / L1SZ, r = i % L1SZ;
  int k = r / HIDDEN, n = r % HIDDEN;
  int kt = k >> 5, quad = (k >> 3) & 3, j = k & 7;
  Wp[l * L1SZ + (((kt*4 + quad) * HIDDEN) + n) * 8 + j] = f2bf(W[i]);
}
__global__ void k_pack_w2(const float* __restrict__ W, short* __restrict__ Wp, int total) {
  int i = blockIdx.x * blockDim.x + threadIdx.x;
  if (i >= total) return;
  int l = i / L2SZ, r = i % L2SZ;
  int k = r / NODE_DIM, n = r % NODE_DIM;
  int kt = k >> 5, quad = (k >> 3) & 3, j = k & 7;
  Wp[l * L2SZ + (((kt*4 + quad) * NODE_DIM) + n) * 8 + j] = f2bf(W[i]);
}

// ---------------- edge MLP: 64 rows/wave MFMA + block-level segmented reduce ----------------
__global__ __launch_bounds__(256, 2) void k_edge_mlp(
    const short* __restrict__ hb,
    const int* __restrict__ se_p, const int* __restrict__ de_p,
    const float* __restrict__ dk_p, const float* __restrict__ sub_w,
    const short* __restrict__ W1p, const float* __restrict__ b1,
    const short* __restrict__ W2p, const float* __restrict__ b2,
    float* __restrict__ agg, int E)
{
  __shared__ short Ys[TE * YS];   // 69632 B; Z (fp32, stride ZS) aliases row-for-row
  __shared__ int   des[TE];

  float* Zs = reinterpret_cast<float*>(Ys);

  const int tid  = threadIdx.x;
  const int lane = tid & 63;
  const int w    = tid >> 6;
  const int quad = lane >> 4;
  const int l16  = lane & 15;
  const int ebase = blockIdx.x * TE;

  // block-wide dst array for the reduce phase
  {
    int ge = ebase + tid;
    des[tid] = (ge < E) ? de_p[ge] : -1;
  }

  // ---- per-lane A-row metadata: rows w*64 + mt*16 + l16 ----
  const short* pd[4];
  const short* ps[4];
  float dk[4];
  #pragma unroll
  for (int mt = 0; mt < 4; ++mt) {
    int r = ebase + w*64 + mt*16 + l16;
    bool v = r < E;
    int se = v ? se_p[r] : 0;
    int de = v ? de_p[r] : 0;
    dk[mt] = v ? dk_p[r] : 0.f;
    pd[mt] = hb + (size_t)de * NODE_DIM;
    ps[mt] = hb + (size_t)se * NODE_DIM;
  }

  // ---- edge-attr A fragments (k = 128 + quad*8 + j) ----
  const int c0 = quad * 8;
  short8 ea[4];
  #pragma unroll
  for (int mt = 0; mt < 4; ++mt) {
    if (quad < 2) {
      float dist = fabsf(dk[mt]);
      #pragma unroll
      for (int j = 0; j < 8; ++j) {
        float t = dist - (float)(c0 + j) * (1.0f / 3.0f);
        ea[mt][j] = f2bf(__expf(-4.5f * t * t));
      }
    } else {
      int kk = (int)(__float_as_uint(dk[mt]) >> 31);
      const float* sw = &sub_w[kk * NUM_GAUSS + (c0 - 16)];
      #pragma unroll
      for (int j = 0; j < 8; ++j) ea[mt][j] = f2bf(sw[j]);
    }
  }

  const int koff = quad * 8;

  // ---- GEMM1: Y[256x128] = silu(X @ W1 + b1), A direct from global ----
  float4v acc1[4][8];
  #pragma unroll
  for (int mt = 0; mt < 4; ++mt)
    #pragma unroll
    for (int nt = 0; nt < 8; ++nt) acc1[mt][nt] = (float4v)0.f;

  #pragma unroll
  for (int kt = 0; kt < 5; ++kt) {
    short8 a[4];
    #pragma unroll
    for (int mt = 0; mt < 4; ++mt) {
      if (kt == 0)      a[mt] = *(const short8*)(pd[mt] + koff);
      else if (kt == 1) a[mt] = *(const short8*)(pd[mt] + 32 + koff);
      else if (kt == 2) a[mt] = *(const short8*)(ps[mt] + koff);
      else if (kt == 3) a[mt] = *(const short8*)(ps[mt] + 32 + koff);
      else              a[mt] = ea[mt];
    }
    #pragma unroll
    for (int nt = 0; nt < 8; ++nt) {
      short8 b = *(const short8*)&W1p[(((kt*4 + quad) * HIDDEN) + nt*16 + l16) * 8];
      #pragma unroll
      for (int mt = 0; mt < 4; ++mt)
        acc1[mt][nt] = __builtin_amdgcn_mfma_f32_16x16x32_bf16(a[mt], b, acc1[mt][nt], 0, 0, 0);
    }
  }

  // bias + silu -> wave-private Y strip in LDS (C-layout -> A-layout)
  #pragma unroll
  for (int nt = 0; nt < 8; ++nt) {
    float bb = b1[nt*16 + l16];
    #pragma unroll
    for (int mt = 0; mt < 4; ++mt)
      #pragma unroll
      for (int r = 0; r < 4; ++r) {
        float y = acc1[mt][nt][r] + bb;
        y = y * __builtin_amdgcn_rcpf(1.f + __expf(-y));
        Ys[(w*64 + mt*16 + quad*4 + r) * YS + nt*16 + l16] = f2bf(y);
      }
  }
  // wave-private rows: within-wave LDS ordering suffices, no barrier

  // ---- GEMM2: Z[256x64] = Y @ W2 ----
  float4v acc2[4][4];
  #pragma unroll
  for (int mt = 0; mt < 4; ++mt)
    #pragma unroll
    for (int nt = 0; nt < 4; ++nt) acc2[mt][nt] = (float4v)0.f;

  #pragma unroll
  for (int kt = 0; kt < 4; ++kt) {
    short8 a[4];
    #pragma unroll
    for (int mt = 0; mt < 4; ++mt)
      a[mt] = *(const short8*)&Ys[(w*64 + mt*16 + l16) * YS + kt*32 + quad*8];
    #pragma unroll
    for (int nt = 0; nt < 4; ++nt) {
      short8 b = *(const short8*)&W2p[(((kt*4 + quad) * NODE_DIM) + nt*16 + l16) * 8];
      #pragma unroll
      for (int mt = 0; mt < 4; ++mt)
        acc2[mt][nt] = __builtin_amdgcn_mfma_f32_16x16x32_bf16(a[mt], b, acc2[mt][nt], 0, 0, 0);
    }
  }

  __syncthreads();   // all Ys reads done before Z overwrites the buffer

  // ---- Z (+b2) -> LDS fp32 ----
  #pragma unroll
  for (int nt = 0; nt < 4; ++nt) {
    float bb = b2[nt*16 + l16];
    #pragma unroll
    for (int mt = 0; mt < 4; ++mt)
      #pragma unroll
      for (int r = 0; r < 4; ++r)
        Zs[(w*64 + mt*16 + quad*4 + r) * ZS + nt*16 + l16] = acc2[mt][nt][r] + bb;
  }
  __syncthreads();

  // ---- segmented reduce over dst-sorted rows: col = tid&63, 64-row chunk = tid>>6 ----
  {
    const int col   = tid & 63;
    const int chunk = tid >> 6;
    const int rbase = chunk * 64;

    int before = (chunk > 0) ? des[rbase - 1]
               : ((ebase > 0) ? de_p[ebase - 1] : -1);

    int   rund  = -2;     // current run's dst (-2: none yet)
    float sum   = 0.f;
    bool  openL = false;  // run continues from before this chunk

    #pragma unroll 4
    for (int i = 0; i < 64; ++i) {
      int d = des[rbase + i];
      if (d != rund) {
        if (rund >= 0) {
          if (openL) atomicAdd(&agg[(size_t)rund * NODE_DIM + col], sum);
          else       agg[(size_t)rund * NODE_DIM + col] = sum;
        }
        rund = d; sum = 0.f;
        openL = (i == 0) && (before == d);
      }
      sum += Zs[(rbase + i) * ZS + col];
    }
    if (rund >= 0) {
      int after = (chunk < 3) ? des[rbase + 64]
                : ((ebase + TE < E) ? de_p[ebase + TE] : -1);
      bool openR = (after == rund);
      if (openL || openR) atomicAdd(&agg[(size_t)rund * NODE_DIM + col], sum);
      else                agg[(size_t)rund * NODE_DIM + col] = sum;
    }
  }
}

// ---------------- residual relu + refresh bf16 mirror + clear agg ----------------
__global__ void k_relu_update(float* __restrict__ hf, short* __restrict__ hb,
                              float* __restrict__ agg, int n4) {
  int stride = gridDim.x * blockDim.x;
  for (int i = blockIdx.x * blockDim.x + threadIdx.x; i < n4; i += stride) {
    float4 a = *reinterpret_cast<float4*>(&agg[i * 4]);
    float4 h = *reinterpret_cast<float4*>(&hf[i * 4]);
    float x0 = fmaxf(h.x + a.x, 0.f), x1 = fmaxf(h.y + a.y, 0.f);
    float x2 = fmaxf(h.z + a.z, 0.f), x3 = fmaxf(h.w + a.w, 0.f);
    *reinterpret_cast<float4*>(&hf[i * 4]) = make_float4(x0, x1, x2, x3);
    unsigned int p0 = ((unsigned int)(unsigned short)f2bf(x1) << 16) | (unsigned short)f2bf(x0);
    unsigned int p1 = ((unsigned int)(unsigned short)f2bf(x3) << 16) | (unsigned short)f2bf(x2);
    *reinterpret_cast<uint2*>(&hb[i * 4]) = make_uint2(p0, p1);
    *reinterpret_cast<float4*>(&agg[i * 4]) = make_float4(0.f, 0.f, 0.f, 0.f);
  }
}

// ---------------- mean pool (batch_ids sorted): wave per 64 nodes ----------------
__global__ void k_pool(const float* __restrict__ h, const int* __restrict__ batch_ids,
                       float* __restrict__ pooled, float* __restrict__ counts, int N) {
  int lane = threadIdx.x & 63;
  int base = blockIdx.x * 64;
  float acc = 0.f;
  int   cnt = 0;
  int  gcur = -1;
  for (int n = 0; n < 64; ++n) {
    int node = base + n;
    if (node >= N) break;
    int g = batch_ids[node];
    if (g != gcur) {
      if (gcur >= 0) {
        atomicAdd(&pooled[gcur * NODE_DIM + lane], acc);
        if (lane == 0) atomicAdd(&counts[gcur], (float)cnt);
      }
      gcur = g; acc = 0.f; cnt = 0;
    }
    acc += h[(size_t)node * NODE_DIM + lane];
    cnt++;
  }
  if (gcur >= 0) {
    atomicAdd(&pooled[gcur * NODE_DIM + lane], acc);
    if (lane == 0) atomicAdd(&counts[gcur], (float)cnt);
  }
}

__global__ void k_final(const float* __restrict__ pooled, const float* __restrict__ counts,
                        const float* __restrict__ fc_w, const float* __restrict__ fc_b,
                        float* __restrict__ out, int G) {
  int g = blockIdx.x * blockDim.x + threadIdx.x;
  if (g < G) {
    float acc = 0.f;
    for (int d = 0; d < NODE_DIM; ++d) acc += pooled[g * NODE_DIM + d] * fc_w[d];
    float c = counts[g];
    if (c < 1.f) c = 1.f;
    out[g] = acc / c + fc_b[0];
  }
}

extern "C" void kernel_launch(void* const* d_in, const int* in_sizes, int n_in,
                              void* d_out, int out_size, void* d_ws, size_t ws_size,
                              hipStream_t stream) {
  const int*   atoms   = (const int*)  d_in[0];
  const int*   eidx    = (const int*)  d_in[1];
  const float* coords  = (const float*)d_in[2];
  const int*   isr     = (const int*)  d_in[3];
  const int*   batch   = (const int*)  d_in[4];
  const float* embed_w = (const float*)d_in[5];
  const float* sub_w   = (const float*)d_in[6];
  const float* W1      = (const float*)d_in[7];
  const float* b1      = (const float*)d_in[8];
  const float* W2      = (const float*)d_in[9];
  const float* b2      = (const float*)d_in[10];
  const float* fc_w    = (const float*)d_in[11];
  const float* fc_b    = (const float*)d_in[12];
  float* out = (float*)d_out;

  const int N = in_sizes[0];
  const int E = in_sizes[1] / 2;
  const int L = in_sizes[8] / HIDDEN;
  const int G = out_size;

  const int* srcv = eidx;
  const int* dstv = eidx + E;

  size_t off = 0;
  auto carve = [&](size_t bytes) -> char* {
    char* p = (char*)d_ws + off;
    off += (bytes + 255) & ~(size_t)255;
    return p;
  };
  float* hf      = (float*)carve((size_t)N * NODE_DIM * 4);
  short* hb      = (short*)carve((size_t)N * NODE_DIM * 2);
  float* agg     = (float*)carve((size_t)N * NODE_DIM * 4);
  float* distk   = (float*)carve((size_t)E * 4);
  int*   cnts    = (int*)  carve((size_t)N * 4);
  int*   cursor  = (int*)  carve((size_t)N * 4);
  int*   se_p    = (int*)  carve((size_t)E * 4);
  int*   de_p    = (int*)  carve((size_t)E * 4);
  float* dk_p    = (float*)carve((size_t)E * 4);
  short* W1p     = (short*)carve((size_t)L * L1SZ * 2);
  short* W2p     = (short*)carve((size_t)L * L2SZ * 2);
  float* pooled  = (float*)carve((size_t)G * NODE_DIM * 4);
  float* cntg    = (float*)carve((size_t)G * 4);

  const int nh = N * NODE_DIM;
  k_init<<<1024, 256, 0, stream>>>(atoms, embed_w, hf, hb, agg, nh);
  k_edge_pre<<<1024, 256, 0, stream>>>(srcv, dstv, coords, isr, distk, E);
  k_zero_i<<<(N + 255) / 256, 256, 0, stream>>>(cnts, N);
  k_zero_f<<<(G * NODE_DIM + G + 255) / 256, 256, 0, stream>>>(pooled, G * NODE_DIM + G);
  k_hist<<<1024, 256, 0, stream>>>(dstv, cnts, E);
  k_scan<<<1, 1024, 0, stream>>>(cnts, cursor, N);
  k_build<<<1024, 256, 0, stream>>>(srcv, dstv, distk, cursor, se_p, de_p, dk_p, E);
  k_pack_w1<<<(L * L1SZ + 255) / 256, 256, 0, stream>>>(W1, W1p, L * L1SZ);
  k_pack_w2<<<(L * L2SZ + 255) / 256, 256, 0, stream>>>(W2, W2p, L * L2SZ);

  const int nblk = (E + TE - 1) / TE;
  for (int l = 0; l < L; ++l) {
    k_edge_mlp<<<nblk, 256, 0, stream>>>(hb, se_p, de_p, dk_p, sub_w,
                                         W1p + (size_t)l * L1SZ, b1 + (size_t)l * HIDDEN,
                                         W2p + (size_t)l * L2SZ, b2 + (size_t)l * NODE_DIM,
                                         agg, E);
    k_relu_update<<<1024, 256, 0, stream>>>(hf, hb, agg, nh / 4);
  }

  k_pool<<<(N + 63) / 64, 64, 0, stream>>>(hf, batch, pooled, cntg, N);
  k_final<<<1, 64, 0, stream>>>(pooled, cntg, fc_w, fc_b, out, G);
}